// Round 11
// baseline (70.646 us; speedup 1.0000x reference)
//
#include <hip/hip_runtime.h>
#include <hip/hip_bf16.h>
#include <stddef.h>

#define R_ 4
#define J_ 6
#define N_ 4096
#define DI_ 128
#define DO_ 64

typedef __bf16 bf16x8 __attribute__((ext_vector_type(8)));
typedef __bf16 bf16x4 __attribute__((ext_vector_type(4)));
typedef float f32x4 __attribute__((ext_vector_type(4)));

static __device__ __forceinline__ bf16x8 cvt8(f32x4 a, f32x4 b) {
    bf16x8 r;
    r[0] = (__bf16)a[0]; r[1] = (__bf16)a[1]; r[2] = (__bf16)a[2]; r[3] = (__bf16)a[3];
    r[4] = (__bf16)b[0]; r[5] = (__bf16)b[1]; r[6] = (__bf16)b[2]; r[7] = (__bf16)b[3];
    return r;
}

// ---------------------------------------------------------------------------
// Kernel 1 (unchanged): y as pre-packed MFMA B-fragments
//   Yf[r][kb=m>>5][ot=o>>4][lane=(o&15)+16*((m&31)>>3)][j=m&7]   (bf16)
// ---------------------------------------------------------------------------
__global__ __launch_bounds__(256) void k_prep(const float* __restrict__ theta,
                                              const float* __restrict__ tt,
                                              const float* __restrict__ x,
                                              const float* __restrict__ fcw,
                                              __bf16* __restrict__ Yf)
{
    const int b = blockIdx.x;
    const int r = b >> 6;
    const int m0 = (b & 63) << 6;
    const int tid = threadIdx.x;
    const int w = tid >> 6, l = tid & 63, lg = l >> 4, lr = l & 15;

    float coef = 0.f;
    #pragma unroll
    for (int j = 0; j < J_; ++j) coef += theta[r * J_ + j] * tt[r * J_ + j];

    const float* wp  = fcw + ((size_t)r * DO_ + w * 16 + lr) * DI_ + lg * 8;
    const float* xp0 = x   + ((size_t)r * N_  + m0     + lr) * DI_ + lg * 8;

    f32x4 acc[4];
    #pragma unroll
    for (int mt = 0; mt < 4; ++mt) acc[mt] = (f32x4)0.0f;

    #pragma unroll
    for (int s = 0; s < 4; ++s) {
        bf16x8 af = cvt8(*(const f32x4*)(wp + s * 32), *(const f32x4*)(wp + s * 32 + 4));
        #pragma unroll
        for (int mt = 0; mt < 4; ++mt) {
            const float* xp = xp0 + (size_t)mt * 16 * DI_ + s * 32;
            bf16x8 bf = cvt8(*(const f32x4*)xp, *(const f32x4*)(xp + 4));
            acc[mt] = __builtin_amdgcn_mfma_f32_16x16x32_bf16(af, bf, acc[mt], 0, 0, 0);
        }
    }

    __shared__ __bf16 ybuf[2][4][64][8];
    #pragma unroll
    for (int mt = 0; mt < 4; ++mt) {
        const int kb2 = mt >> 1;
        const int hi  = ((mt & 1) << 1) + (lr >> 3);
        const int j   = lr & 7;
        #pragma unroll
        for (int i = 0; i < 4; ++i)
            ybuf[kb2][w][lg * 4 + i + (hi << 4)][j] = (__bf16)(coef * acc[mt][i]);
    }
    __syncthreads();

    const __bf16* yb = &ybuf[0][0][0][0];
    __bf16* dst = Yf + (size_t)r * (DO_ * N_) + (size_t)(m0 >> 5) * 2048;
    *(bf16x8*)(dst + tid * 8)        = *(const bf16x8*)(yb + tid * 8);
    *(bf16x8*)(dst + 2048 + tid * 8) = *(const bf16x8*)(yb + 2048 + tid * 8);
}

// ---------------------------------------------------------------------------
// Kernel 2: u[r][n][o] = prelu( sum_m a[r][n][m] * y[r][m][o] + fc_b[r][o] )
// BK=256 restructure (DRAM-granule theory): 256 blocks x 256 threads (4
// waves), BM=64, NO K-split — wave wv owns o-tile wv over the FULL K.
// Per chunk: stage 64 rows x 256 k (32KB) double-buffered; each A row is
// visited with 1KB per chunk (16 visits) instead of 256B (32 visits) ->
// 4x fewer DRAM row activations per byte. All sub-mechanisms identical to
// proven round 7: 4-row x 256B coalesced segments, cvt-at-staging,
// (row&7)<<4 involution both LDS sides, LDS-only barrier, depth-1 reg
// prefetch, packed-Y 1KB fragment loads (lockstep -> L2-shared).
// Epilogue: acc -> LDS transpose (freed abuf) -> coalesced U stores.
// ---------------------------------------------------------------------------
__global__ __launch_bounds__(256, 2) void k_diff(const float* __restrict__ A,
                                                 const __bf16* __restrict__ Yf,
                                                 const float* __restrict__ fcb,
                                                 const float* __restrict__ p0p,
                                                 float* __restrict__ U)
{
    const int b = blockIdx.x;
    const int r = b >> 6;
    const int n0 = (b & 63) << 6;
    const int tid = threadIdx.x;
    const int wv = tid >> 6, l = tid & 63, lg = l >> 4, lr = l & 15;

    __shared__ __bf16 abuf[2][64 * 256];   // [parity][row][k]  2 x 32KB

    // --- staging geometry: wave wv stages rows wv*16 .. +15, all 256 cols ---
    const int srow = l >> 4;            // 0..3
    const int scol = (l & 15) * 4;      // float col within a 64-col sub-block
    const float* Abl = A + ((size_t)r * N_ + n0 + wv * 16 + srow) * N_ + scol;

    int wo[4][4];                       // [sc][j] LDS write offs (bf16 elems)
    #pragma unroll
    for (int sc = 0; sc < 4; ++sc)
        #pragma unroll
        for (int j = 0; j < 4; ++j) {
            const int row = wv * 16 + 4 * j + srow;
            wo[sc][j] = row * 256 + sc * 64 + (((scol * 2) ^ ((row & 7) << 4)) >> 1);
        }

    // --- fragment read offsets: row = mt*16+lr; + sub*64 at use site ---
    const int q = (lr & 7) << 4;
    int ro[4][2];
    #pragma unroll
    for (int mt = 0; mt < 4; ++mt)
        #pragma unroll
        for (int ss = 0; ss < 2; ++ss)
            ro[mt][ss] = (mt * 16 + lr) * 256 + (((ss * 64 + lg * 16) ^ q) >> 1);

    // --- Y fragment base for this wave's ot = wv ---
    const __bf16* yb0 = Yf + (size_t)r * (DO_ * N_) + (size_t)wv * 512 + (size_t)l * 8;

    f32x4 acc[4];
    #pragma unroll
    for (int mt = 0; mt < 4; ++mt) acc[mt] = (f32x4)0.0f;

#define LOADRG(c) {                                                        \
        _Pragma("unroll")                                                  \
        for (int sc = 0; sc < 4; ++sc)                                     \
            _Pragma("unroll")                                              \
            for (int j = 0; j < 4; ++j)                                    \
                rg[sc][j] = *(const f32x4*)(Abl + (size_t)(4 * j) * N_ + (c) * 256 + sc * 64); \
    }
#define STAGE(par) {                                                       \
        __bf16* ab = &abuf[par][0];                                        \
        _Pragma("unroll")                                                  \
        for (int sc = 0; sc < 4; ++sc)                                     \
            _Pragma("unroll")                                              \
            for (int j = 0; j < 4; ++j) {                                  \
                bf16x4 cv;                                                 \
                cv[0] = (__bf16)rg[sc][j][0]; cv[1] = (__bf16)rg[sc][j][1];\
                cv[2] = (__bf16)rg[sc][j][2]; cv[3] = (__bf16)rg[sc][j][3];\
                *(bf16x4*)&ab[wo[sc][j]] = cv;                             \
            }                                                              \
    }
#define BODY(c, par) {                                                     \
        const __bf16* abr = &abuf[par][0];                                 \
        _Pragma("unroll")                                                  \
        for (int sub = 0; sub < 4; ++sub)                                  \
            _Pragma("unroll")                                              \
            for (int ss = 0; ss < 2; ++ss) {                               \
                bf16x8 bfr = *(const bf16x8*)(yb0 + (size_t)((c) * 8 + sub * 2 + ss) * 2048); \
                _Pragma("unroll")                                          \
                for (int mt = 0; mt < 4; ++mt) {                           \
                    bf16x8 af = *(const bf16x8*)&abr[ro[mt][ss] + sub * 64]; \
                    acc[mt] = __builtin_amdgcn_mfma_f32_16x16x32_bf16(af, bfr, acc[mt], 0, 0, 0); \
                }                                                          \
            }                                                              \
    }
#define LDSBAR() {                                                         \
        asm volatile("s_waitcnt lgkmcnt(0)" ::: "memory");                 \
        __builtin_amdgcn_s_barrier();                                      \
        __builtin_amdgcn_sched_barrier(0);                                 \
    }

    f32x4 rg[4][4];
    LOADRG(0);

    for (int c = 0; c < 16; ++c) {
        STAGE(c & 1);
        if (c < 15) LOADRG(c + 1);
        LDSBAR();
        BODY(c, c & 1);
    }

#undef LOADRG
#undef STAGE
#undef BODY
#undef LDSBAR

    // --- epilogue: transpose acc through freed abuf (parity-0 region only;
    // safe: parity-0 reads drained at the c=15 barrier, last BODY reads p1) ---
    float* ub = (float*)&abuf[0][0];    // [64][68] floats, 17.4KB < 32KB
    #pragma unroll
    for (int mt = 0; mt < 4; ++mt)
        #pragma unroll
        for (int i = 0; i < 4; ++i)
            ub[(mt * 16 + lg * 4 + i) * 68 + wv * 16 + lr] = acc[mt][i];
    __syncthreads();

    const float p0 = *p0p;
    const int n  = tid >> 2;
    const int ob = (tid & 3) * 16;
    float* Un = &U[((size_t)r * N_ + n0 + n) * DO_ + ob];
    #pragma unroll
    for (int k = 0; k < 4; ++k) {
        f32x4 s4 = *(const f32x4*)&ub[n * 68 + ob + k * 4];
        f32x4 uv;
        #pragma unroll
        for (int j = 0; j < 4; ++j) {
            const float v = s4[j] + fcb[r * DO_ + ob + k * 4 + j];
            uv[j] = v >= 0.f ? v : p0 * v;
        }
        *(f32x4*)&Un[k * 4] = uv;
    }
}

// ---------------------------------------------------------------------------
// Kernel 3 (unchanged): h = prelu(conv_w @ u + conv_b)
// ---------------------------------------------------------------------------
__global__ __launch_bounds__(256) void k_conv(const float* __restrict__ U,
                                              const float* __restrict__ cw,
                                              const float* __restrict__ cb,
                                              const float* __restrict__ p1p,
                                              float* __restrict__ H)
{
    const size_t t = (size_t)blockIdx.x * 256 + threadIdx.x;
    const size_t base = t * 4;
    const size_t SL = (size_t)N_ * DO_;  // 262144

    f32x4 u0 = *(const f32x4*)&U[base];
    f32x4 u1 = *(const f32x4*)&U[base + SL];
    f32x4 u2 = *(const f32x4*)&U[base + 2 * SL];
    f32x4 u3 = *(const f32x4*)&U[base + 3 * SL];
    const float p1 = *p1p;

    #pragma unroll
    for (int qq = 0; qq < 4; ++qq) {
        f32x4 hv = cw[qq * 4 + 0] * u0 + cw[qq * 4 + 1] * u1 +
                   cw[qq * 4 + 2] * u2 + cw[qq * 4 + 3] * u3;
        const float bq = cb[qq];
        f32x4 ho;
        #pragma unroll
        for (int j = 0; j < 4; ++j) {
            const float v = hv[j] + bq;
            ho[j] = v >= 0.f ? v : p1 * v;
        }
        *(f32x4*)&H[qq * SL + base] = ho;
    }
}

extern "C" void kernel_launch(void* const* d_in, const int* in_sizes, int n_in,
                              void* d_out, int out_size, void* d_ws, size_t ws_size,
                              hipStream_t stream)
{
    const float* theta = (const float*)d_in[0];
    const float* tt    = (const float*)d_in[1];
    const float* a     = (const float*)d_in[2];
    const float* x     = (const float*)d_in[3];
    const float* fcw   = (const float*)d_in[4];
    const float* fcb   = (const float*)d_in[5];
    const float* cw    = (const float*)d_in[6];
    const float* cb    = (const float*)d_in[7];
    const float* p0    = (const float*)d_in[8];
    const float* p1    = (const float*)d_in[9];

    float* out = (float*)d_out;
    float* H = out;                              // output 0: h  [R,N,DO]
    float* U = out + (size_t)R_ * N_ * DO_;      // output 1: u  [R,N,DO]

    const size_t ybytes = (size_t)R_ * DO_ * N_ * sizeof(__bf16);
    __bf16* Y = (ws_size >= ybytes) ? (__bf16*)d_ws : (__bf16*)H;

    k_prep<<<dim3(256), dim3(256), 0, stream>>>(theta, tt, x, fcw, Y);
    k_diff<<<dim3(256), dim3(256), 0, stream>>>(a, Y, fcb, p0, U);
    k_conv<<<dim3(256), dim3(256), 0, stream>>>(U, cw, cb, p1, H);
}

// Round 12
// 68.089 us; speedup vs baseline: 1.0376x; 1.0376x over previous
//
#include <hip/hip_runtime.h>
#include <hip/hip_bf16.h>
#include <stddef.h>

#define R_ 4
#define J_ 6
#define N_ 4096
#define DI_ 128
#define DO_ 64

typedef __bf16 bf16x8 __attribute__((ext_vector_type(8)));
typedef __bf16 bf16x4 __attribute__((ext_vector_type(4)));
typedef float f32x4 __attribute__((ext_vector_type(4)));

static __device__ __forceinline__ bf16x8 cvt8(f32x4 a, f32x4 b) {
    bf16x8 r;
    r[0] = (__bf16)a[0]; r[1] = (__bf16)a[1]; r[2] = (__bf16)a[2]; r[3] = (__bf16)a[3];
    r[4] = (__bf16)b[0]; r[5] = (__bf16)b[1]; r[6] = (__bf16)b[2]; r[7] = (__bf16)b[3];
    return r;
}

// ---------------------------------------------------------------------------
// Kernel 1 (unchanged): y as pre-packed MFMA B-fragments
//   Yf[r][kb=m>>5][ot=o>>4][lane=(o&15)+16*((m&31)>>3)][j=m&7]   (bf16)
// ---------------------------------------------------------------------------
__global__ __launch_bounds__(256) void k_prep(const float* __restrict__ theta,
                                              const float* __restrict__ tt,
                                              const float* __restrict__ x,
                                              const float* __restrict__ fcw,
                                              __bf16* __restrict__ Yf)
{
    const int b = blockIdx.x;
    const int r = b >> 6;
    const int m0 = (b & 63) << 6;
    const int tid = threadIdx.x;
    const int w = tid >> 6, l = tid & 63, lg = l >> 4, lr = l & 15;

    float coef = 0.f;
    #pragma unroll
    for (int j = 0; j < J_; ++j) coef += theta[r * J_ + j] * tt[r * J_ + j];

    const float* wp  = fcw + ((size_t)r * DO_ + w * 16 + lr) * DI_ + lg * 8;
    const float* xp0 = x   + ((size_t)r * N_  + m0     + lr) * DI_ + lg * 8;

    f32x4 acc[4];
    #pragma unroll
    for (int mt = 0; mt < 4; ++mt) acc[mt] = (f32x4)0.0f;

    #pragma unroll
    for (int s = 0; s < 4; ++s) {
        bf16x8 af = cvt8(*(const f32x4*)(wp + s * 32), *(const f32x4*)(wp + s * 32 + 4));
        #pragma unroll
        for (int mt = 0; mt < 4; ++mt) {
            const float* xp = xp0 + (size_t)mt * 16 * DI_ + s * 32;
            bf16x8 bf = cvt8(*(const f32x4*)xp, *(const f32x4*)(xp + 4));
            acc[mt] = __builtin_amdgcn_mfma_f32_16x16x32_bf16(af, bf, acc[mt], 0, 0, 0);
        }
    }

    __shared__ __bf16 ybuf[2][4][64][8];
    #pragma unroll
    for (int mt = 0; mt < 4; ++mt) {
        const int kb2 = mt >> 1;
        const int hi  = ((mt & 1) << 1) + (lr >> 3);
        const int j   = lr & 7;
        #pragma unroll
        for (int i = 0; i < 4; ++i)
            ybuf[kb2][w][lg * 4 + i + (hi << 4)][j] = (__bf16)(coef * acc[mt][i]);
    }
    __syncthreads();

    const __bf16* yb = &ybuf[0][0][0][0];
    __bf16* dst = Yf + (size_t)r * (DO_ * N_) + (size_t)(m0 >> 5) * 2048;
    *(bf16x8*)(dst + tid * 8)        = *(const bf16x8*)(yb + tid * 8);
    *(bf16x8*)(dst + 2048 + tid * 8) = *(const bf16x8*)(yb + 2048 + tid * 8);
}

// ---------------------------------------------------------------------------
// Kernel 2: u[r][n][o] = prelu( sum_m a[r][n][m] * y[r][m][o] + fc_b[r][o] )
// ONE-SEGMENT-LOAD restructure: BM=32, BK=256, 512 blocks x 256 threads
// (4 waves = 4 o-tiles, full K each, no K-split/red buffer).
//   - A loads: wave w stages rows w*8..w*8+7; each load instruction = 64
//     lanes x 16B CONTIGUOUS within one row (lane l -> col l*4) — the copy-
//     ubench pattern (1 segment/instr vs 4 in all prior rounds). Bonus: 1KB
//     DRAM granularity per row visit.
//   - LDS [2][32][256] bf16 (2x16KB dbuf); involution byte^(row&7)<<4:
//     write = 64-lane bijection over the row's 512B; frag reads 2-way (free).
//   - Y fragment loads hoisted BEFORE the barrier (pure-VGPR dest, overlaps
//     barrier wait); LDS-only barrier + depth-1 reg prefetch as r7.
//   - Epilogue: acc -> freed-LDS transpose -> coalesced f32x4 U stores.
// ---------------------------------------------------------------------------
__global__ __launch_bounds__(256, 2) void k_diff(const float* __restrict__ A,
                                                 const __bf16* __restrict__ Yf,
                                                 const float* __restrict__ fcb,
                                                 const float* __restrict__ p0p,
                                                 float* __restrict__ U)
{
    const int b = blockIdx.x;
    const int r = b >> 7;
    const int n0 = (b & 127) << 5;
    const int tid = threadIdx.x;
    const int w = tid >> 6, l = tid & 63, lg = l >> 4, lr = l & 15;

    __shared__ __bf16 abuf[2][32 * 256];   // [parity][row][k]  2 x 16KB

    // A staging: base of row w*8, lane-contiguous cols
    const float* Abl = A + ((size_t)r * N_ + n0 + w * 8) * N_ + l * 4;

    // LDS write offsets (bf16 elems): row = w*8+i, (row&7) == i
    int wo[8];
    #pragma unroll
    for (int i = 0; i < 8; ++i)
        wo[i] = (w * 8 + i) * 256 + (((l * 8) ^ (i << 4)) >> 1);

    // fragment read col offsets (bf16 elems) per k-subtile
    const int q = (lr & 7) << 4;
    int col8[8];
    #pragma unroll
    for (int ks = 0; ks < 8; ++ks)
        col8[ks] = (((ks * 64 + lg * 16)) ^ q) >> 1;

    // Y fragment base: this wave's ot = w
    const __bf16* yb0 = Yf + (size_t)r * (DO_ * N_) + (size_t)w * 512 + (size_t)l * 8;

    f32x4 acc[2];
    acc[0] = (f32x4)0.0f; acc[1] = (f32x4)0.0f;

    f32x4 rg[8];
    bf16x8 bfr[8];

#define LOADRG(c) {                                                        \
        _Pragma("unroll")                                                  \
        for (int i = 0; i < 8; ++i)                                        \
            rg[i] = *(const f32x4*)(Abl + (size_t)i * N_ + (c) * 256);     \
    }
#define STAGE(par) {                                                       \
        __bf16* ab = &abuf[par][0];                                        \
        _Pragma("unroll")                                                  \
        for (int i = 0; i < 8; ++i) {                                      \
            bf16x4 cv;                                                     \
            cv[0] = (__bf16)rg[i][0]; cv[1] = (__bf16)rg[i][1];            \
            cv[2] = (__bf16)rg[i][2]; cv[3] = (__bf16)rg[i][3];            \
            *(bf16x4*)&ab[wo[i]] = cv;                                     \
        }                                                                  \
    }
#define YLOAD(c) {                                                         \
        _Pragma("unroll")                                                  \
        for (int ks = 0; ks < 8; ++ks)                                     \
            bfr[ks] = *(const bf16x8*)(yb0 + (size_t)((c) * 8 + ks) * 2048); \
    }
#define BODY(par) {                                                        \
        const __bf16* abr = &abuf[par][0];                                 \
        _Pragma("unroll")                                                  \
        for (int ks = 0; ks < 8; ++ks)                                     \
            _Pragma("unroll")                                              \
            for (int mt = 0; mt < 2; ++mt) {                               \
                bf16x8 af = *(const bf16x8*)&abr[(mt * 16 + lr) * 256 + col8[ks]]; \
                acc[mt] = __builtin_amdgcn_mfma_f32_16x16x32_bf16(af, bfr[ks], acc[mt], 0, 0, 0); \
            }                                                              \
    }

    LOADRG(0);
    for (int c = 0; c < 16; ++c) {
        STAGE(c & 1);
        YLOAD(c);                    // VGPR-dest; overlaps the barrier wait
        if (c < 15) LOADRG(c + 1);
        asm volatile("s_waitcnt lgkmcnt(0)" ::: "memory");
        __builtin_amdgcn_s_barrier();
        __builtin_amdgcn_sched_barrier(0);
        BODY(c & 1);
    }

#undef LOADRG
#undef STAGE
#undef YLOAD
#undef BODY

    // epilogue: transpose through freed parity-0 LDS (last BODY read par 1)
    float* ub = (float*)&abuf[0][0];          // [32][72] floats, 9.2KB
    #pragma unroll
    for (int mt = 0; mt < 2; ++mt)
        #pragma unroll
        for (int i = 0; i < 4; ++i)
            ub[(mt * 16 + lg * 4 + i) * 72 + w * 16 + lr] = acc[mt][i];
    __syncthreads();

    const float p0 = *p0p;
    const int n  = tid >> 3;
    const int oc = (tid & 7) * 8;
    float* Un = &U[((size_t)r * N_ + n0 + n) * DO_ + oc];
    #pragma unroll
    for (int h = 0; h < 2; ++h) {
        f32x4 s4 = *(const f32x4*)&ub[n * 72 + oc + h * 4];
        f32x4 uv;
        #pragma unroll
        for (int j = 0; j < 4; ++j) {
            const float v = s4[j] + fcb[r * DO_ + oc + h * 4 + j];
            uv[j] = v >= 0.f ? v : p0 * v;
        }
        *(f32x4*)&Un[h * 4] = uv;
    }
}

// ---------------------------------------------------------------------------
// Kernel 3 (unchanged): h = prelu(conv_w @ u + conv_b)
// ---------------------------------------------------------------------------
__global__ __launch_bounds__(256) void k_conv(const float* __restrict__ U,
                                              const float* __restrict__ cw,
                                              const float* __restrict__ cb,
                                              const float* __restrict__ p1p,
                                              float* __restrict__ H)
{
    const size_t t = (size_t)blockIdx.x * 256 + threadIdx.x;
    const size_t base = t * 4;
    const size_t SL = (size_t)N_ * DO_;  // 262144

    f32x4 u0 = *(const f32x4*)&U[base];
    f32x4 u1 = *(const f32x4*)&U[base + SL];
    f32x4 u2 = *(const f32x4*)&U[base + 2 * SL];
    f32x4 u3 = *(const f32x4*)&U[base + 3 * SL];
    const float p1 = *p1p;

    #pragma unroll
    for (int qq = 0; qq < 4; ++qq) {
        f32x4 hv = cw[qq * 4 + 0] * u0 + cw[qq * 4 + 1] * u1 +
                   cw[qq * 4 + 2] * u2 + cw[qq * 4 + 3] * u3;
        const float bq = cb[qq];
        f32x4 ho;
        #pragma unroll
        for (int j = 0; j < 4; ++j) {
            const float v = hv[j] + bq;
            ho[j] = v >= 0.f ? v : p1 * v;
        }
        *(f32x4*)&H[qq * SL + base] = ho;
    }
}

extern "C" void kernel_launch(void* const* d_in, const int* in_sizes, int n_in,
                              void* d_out, int out_size, void* d_ws, size_t ws_size,
                              hipStream_t stream)
{
    const float* theta = (const float*)d_in[0];
    const float* tt    = (const float*)d_in[1];
    const float* a     = (const float*)d_in[2];
    const float* x     = (const float*)d_in[3];
    const float* fcw   = (const float*)d_in[4];
    const float* fcb   = (const float*)d_in[5];
    const float* cw    = (const float*)d_in[6];
    const float* cb    = (const float*)d_in[7];
    const float* p0    = (const float*)d_in[8];
    const float* p1    = (const float*)d_in[9];

    float* out = (float*)d_out;
    float* H = out;                              // output 0: h  [R,N,DO]
    float* U = out + (size_t)R_ * N_ * DO_;      // output 1: u  [R,N,DO]

    const size_t ybytes = (size_t)R_ * DO_ * N_ * sizeof(__bf16);
    __bf16* Y = (ws_size >= ybytes) ? (__bf16*)d_ws : (__bf16*)H;

    k_prep<<<dim3(256), dim3(256), 0, stream>>>(theta, tt, x, fcw, Y);
    k_diff<<<dim3(512), dim3(256), 0, stream>>>(a, Y, fcb, p0, U);
    k_conv<<<dim3(256), dim3(256), 0, stream>>>(U, cw, cb, p1, H);
}

// Round 13
// 58.532 us; speedup vs baseline: 1.2070x; 1.1633x over previous
//
#include <hip/hip_runtime.h>
#include <hip/hip_bf16.h>
#include <stddef.h>

#define R_ 4
#define J_ 6
#define N_ 4096
#define DI_ 128
#define DO_ 64

typedef __bf16 bf16x8 __attribute__((ext_vector_type(8)));
typedef __bf16 bf16x4 __attribute__((ext_vector_type(4)));
typedef float f32x4 __attribute__((ext_vector_type(4)));

static __device__ __forceinline__ bf16x8 cvt8(f32x4 a, f32x4 b) {
    bf16x8 r;
    r[0] = (__bf16)a[0]; r[1] = (__bf16)a[1]; r[2] = (__bf16)a[2]; r[3] = (__bf16)a[3];
    r[4] = (__bf16)b[0]; r[5] = (__bf16)b[1]; r[6] = (__bf16)b[2]; r[7] = (__bf16)b[3];
    return r;
}

// ---------------------------------------------------------------------------
// Kernel 1 (unchanged): y as pre-packed MFMA B-fragments
//   Yf[r][kb=m>>5][ot=o>>4][lane=(o&15)+16*((m&31)>>3)][j=m&7]   (bf16)
// ---------------------------------------------------------------------------
__global__ __launch_bounds__(256) void k_prep(const float* __restrict__ theta,
                                              const float* __restrict__ tt,
                                              const float* __restrict__ x,
                                              const float* __restrict__ fcw,
                                              __bf16* __restrict__ Yf)
{
    const int b = blockIdx.x;
    const int r = b >> 6;
    const int m0 = (b & 63) << 6;
    const int tid = threadIdx.x;
    const int w = tid >> 6, l = tid & 63, lg = l >> 4, lr = l & 15;

    float coef = 0.f;
    #pragma unroll
    for (int j = 0; j < J_; ++j) coef += theta[r * J_ + j] * tt[r * J_ + j];

    const float* wp  = fcw + ((size_t)r * DO_ + w * 16 + lr) * DI_ + lg * 8;
    const float* xp0 = x   + ((size_t)r * N_  + m0     + lr) * DI_ + lg * 8;

    f32x4 acc[4];
    #pragma unroll
    for (int mt = 0; mt < 4; ++mt) acc[mt] = (f32x4)0.0f;

    #pragma unroll
    for (int s = 0; s < 4; ++s) {
        bf16x8 af = cvt8(*(const f32x4*)(wp + s * 32), *(const f32x4*)(wp + s * 32 + 4));
        #pragma unroll
        for (int mt = 0; mt < 4; ++mt) {
            const float* xp = xp0 + (size_t)mt * 16 * DI_ + s * 32;
            bf16x8 bf = cvt8(*(const f32x4*)xp, *(const f32x4*)(xp + 4));
            acc[mt] = __builtin_amdgcn_mfma_f32_16x16x32_bf16(af, bf, acc[mt], 0, 0, 0);
        }
    }

    __shared__ __bf16 ybuf[2][4][64][8];
    #pragma unroll
    for (int mt = 0; mt < 4; ++mt) {
        const int kb2 = mt >> 1;
        const int hi  = ((mt & 1) << 1) + (lr >> 3);
        const int j   = lr & 7;
        #pragma unroll
        for (int i = 0; i < 4; ++i)
            ybuf[kb2][w][lg * 4 + i + (hi << 4)][j] = (__bf16)(coef * acc[mt][i]);
    }
    __syncthreads();

    const __bf16* yb = &ybuf[0][0][0][0];
    __bf16* dst = Yf + (size_t)r * (DO_ * N_) + (size_t)(m0 >> 5) * 2048;
    *(bf16x8*)(dst + tid * 8)        = *(const bf16x8*)(yb + tid * 8);
    *(bf16x8*)(dst + 2048 + tid * 8) = *(const bf16x8*)(yb + 2048 + tid * 8);
}

// ---------------------------------------------------------------------------
// Kernel 2: u[r][n][o] = prelu( sum_m a[r][n][m] * y[r][m][o] + fc_b[r][o] )
// r7 base (BM=64, 8 waves = ot x kh, dbuf swizzled LDS, LDS-only barrier)
// with ONE change: register DOUBLE-BUFFER FOR Y. Y fragments for chunk c+1
// are issued BEFORE BODY(c) consumes chunk c's (named yA/yB buffers, static
// indexing), so the post-barrier Y-load -> MFMA L2-latency chain (~2x200cy
// per chunk = the measured 470cy/chunk slack) is hidden by a full iteration.
// A-path/accumulation order byte-identical to r7 -> absmax 1.0.
// ---------------------------------------------------------------------------
__global__ __launch_bounds__(512, 2) void k_diff(const float* __restrict__ A,
                                                 const __bf16* __restrict__ Yf,
                                                 const float* __restrict__ fcb,
                                                 const float* __restrict__ p0p,
                                                 float* __restrict__ U)
{
    const int b = blockIdx.x;
    const int r = b >> 6;
    const int n0 = (b & 63) << 6;
    const int tid = threadIdx.x;
    const int w = tid >> 6, l = tid & 63, lg = l >> 4, lr = l & 15;
    const int kh = w >> 2, ot = w & 3;

    __shared__ __bf16 abuf[2][2][64 * 64];           // [kh][parity][row][k]
    __shared__ __align__(16) float red[8][64][20];

    const int srow = l >> 4;
    const int scol = (l & 15) * 4;
    const float* Abl = A + ((size_t)r * N_ + n0 + ot * 16 + srow) * N_
                         + (size_t)kh * 2048 + scol;

    int wo[4];
    #pragma unroll
    for (int j = 0; j < 4; ++j) {
        const int row = ot * 16 + 4 * j + srow;
        wo[j] = row * 64 + (((scol * 2) ^ ((row & 7) << 4)) >> 1);
    }

    const int q = (lr & 7) << 4;
    int ro[4][2];
    #pragma unroll
    for (int mt = 0; mt < 4; ++mt)
        #pragma unroll
        for (int ss = 0; ss < 2; ++ss)
            ro[mt][ss] = (mt * 16 + lr) * 64 + (((ss * 64 + lg * 16) ^ q) >> 1);

    const __bf16* yb0 = Yf + (size_t)r * (DO_ * N_) + (size_t)kh * 64 * 2048
                           + (size_t)ot * 512 + (size_t)l * 8;

    f32x4 acc[4];
    #pragma unroll
    for (int mt = 0; mt < 4; ++mt) acc[mt] = (f32x4)0.0f;

#define LOADRG(dst, c) {                                                   \
        _Pragma("unroll")                                                  \
        for (int j = 0; j < 4; ++j)                                        \
            dst[j] = *(const f32x4*)(Abl + (size_t)(4 * j) * N_ + (c) * 64); \
    }
#define YLOAD(dst, c) {                                                    \
        dst[0] = *(const bf16x8*)(yb0 + (size_t)((c) * 2 + 0) * 2048);     \
        dst[1] = *(const bf16x8*)(yb0 + (size_t)((c) * 2 + 1) * 2048);     \
    }
#define STAGE(src, par) {                                                  \
        __bf16* ab = &abuf[kh][par][0];                                    \
        _Pragma("unroll")                                                  \
        for (int j = 0; j < 4; ++j) {                                      \
            bf16x4 cv;                                                     \
            cv[0] = (__bf16)src[j][0]; cv[1] = (__bf16)src[j][1];          \
            cv[2] = (__bf16)src[j][2]; cv[3] = (__bf16)src[j][3];          \
            *(bf16x4*)&ab[wo[j]] = cv;                                     \
        }                                                                  \
    }
#define BODY(yfr, par) {                                                   \
        const __bf16* abr = &abuf[kh][par][0];                             \
        _Pragma("unroll")                                                  \
        for (int ss = 0; ss < 2; ++ss) {                                   \
            _Pragma("unroll")                                              \
            for (int mt = 0; mt < 4; ++mt) {                               \
                bf16x8 af = *(const bf16x8*)&abr[ro[mt][ss]];              \
                acc[mt] = __builtin_amdgcn_mfma_f32_16x16x32_bf16(af, yfr[ss], acc[mt], 0, 0, 0); \
            }                                                              \
        }                                                                  \
    }
#define LDSBAR() {                                                         \
        asm volatile("s_waitcnt lgkmcnt(0)" ::: "memory");                 \
        __builtin_amdgcn_s_barrier();                                      \
        __builtin_amdgcn_sched_barrier(0);                                 \
    }

    f32x4 rgA[4], rgB[4];
    bf16x8 yA[2], yB[2];
    LOADRG(rgA, 0);
    LOADRG(rgB, 1);
    YLOAD(yA, 0);

    for (int c = 0; c < 32; c += 2) {
        // even chunk c -> parity 0; consume yA, prefetch yB for c+1
        STAGE(rgA, 0);
        if (c + 2 < 32) LOADRG(rgA, c + 2);
        YLOAD(yB, c + 1);
        LDSBAR();
        BODY(yA, 0);
        // odd chunk c+1 -> parity 1; consume yB, prefetch yA for c+2
        STAGE(rgB, 1);
        if (c + 3 < 32) LOADRG(rgB, c + 3);
        if (c + 2 < 32) YLOAD(yA, c + 2);
        LDSBAR();
        BODY(yB, 1);
    }

#undef LOADRG
#undef YLOAD
#undef STAGE
#undef BODY
#undef LDSBAR

    #pragma unroll
    for (int mt = 0; mt < 4; ++mt)
        #pragma unroll
        for (int i = 0; i < 4; ++i)
            red[w][mt * 16 + lg * 4 + i][lr] = acc[mt][i];
    __syncthreads();

    const float p0 = *p0p;
    #pragma unroll
    for (int idx = tid; idx < 1024; idx += 512) {
        const int n  = idx >> 4;
        const int oq = idx & 15;
        const int t2 = oq >> 2;
        const int oo = (oq & 3) * 4;
        f32x4 s4 = *(const f32x4*)&red[t2][n][oo] + *(const f32x4*)&red[t2 + 4][n][oo];
        const int o = t2 * 16 + oo;
        f32x4 uv;
        #pragma unroll
        for (int j = 0; j < 4; ++j) {
            const float v = s4[j] + fcb[r * DO_ + o + j];
            uv[j] = v >= 0.f ? v : p0 * v;
        }
        *(f32x4*)&U[((size_t)r * N_ + n0 + n) * DO_ + o] = uv;
    }
}

// ---------------------------------------------------------------------------
// Kernel 3 (unchanged): h = prelu(conv_w @ u + conv_b)
// ---------------------------------------------------------------------------
__global__ __launch_bounds__(256) void k_conv(const float* __restrict__ U,
                                              const float* __restrict__ cw,
                                              const float* __restrict__ cb,
                                              const float* __restrict__ p1p,
                                              float* __restrict__ H)
{
    const size_t t = (size_t)blockIdx.x * 256 + threadIdx.x;
    const size_t base = t * 4;
    const size_t SL = (size_t)N_ * DO_;  // 262144

    f32x4 u0 = *(const f32x4*)&U[base];
    f32x4 u1 = *(const f32x4*)&U[base + SL];
    f32x4 u2 = *(const f32x4*)&U[base + 2 * SL];
    f32x4 u3 = *(const f32x4*)&U[base + 3 * SL];
    const float p1 = *p1p;

    #pragma unroll
    for (int qq = 0; qq < 4; ++qq) {
        f32x4 hv = cw[qq * 4 + 0] * u0 + cw[qq * 4 + 1] * u1 +
                   cw[qq * 4 + 2] * u2 + cw[qq * 4 + 3] * u3;
        const float bq = cb[qq];
        f32x4 ho;
        #pragma unroll
        for (int j = 0; j < 4; ++j) {
            const float v = hv[j] + bq;
            ho[j] = v >= 0.f ? v : p1 * v;
        }
        *(f32x4*)&H[qq * SL + base] = ho;
    }
}

extern "C" void kernel_launch(void* const* d_in, const int* in_sizes, int n_in,
                              void* d_out, int out_size, void* d_ws, size_t ws_size,
                              hipStream_t stream)
{
    const float* theta = (const float*)d_in[0];
    const float* tt    = (const float*)d_in[1];
    const float* a     = (const float*)d_in[2];
    const float* x     = (const float*)d_in[3];
    const float* fcw   = (const float*)d_in[4];
    const float* fcb   = (const float*)d_in[5];
    const float* cw    = (const float*)d_in[6];
    const float* cb    = (const float*)d_in[7];
    const float* p0    = (const float*)d_in[8];
    const float* p1    = (const float*)d_in[9];

    float* out = (float*)d_out;
    float* H = out;                              // output 0: h  [R,N,DO]
    float* U = out + (size_t)R_ * N_ * DO_;      // output 1: u  [R,N,DO]

    const size_t ybytes = (size_t)R_ * DO_ * N_ * sizeof(__bf16);
    __bf16* Y = (ws_size >= ybytes) ? (__bf16*)d_ws : (__bf16*)H;

    k_prep<<<dim3(256), dim3(256), 0, stream>>>(theta, tt, x, fcw, Y);
    k_diff<<<dim3(256), dim3(512), 0, stream>>>(a, Y, fcb, p0, U);
    k_conv<<<dim3(256), dim3(256), 0, stream>>>(U, cw, cb, p1, H);
}